// Round 3
// baseline (299.741 us; speedup 1.0000x reference)
//
#include <hip/hip_runtime.h>
#include <hip/hip_fp16.h>
#include <math.h>

#define N_NODES 50000
#define N_EDGES 800000
#define IN_FEATS 128
#define N_HIDDEN 64
#define OUT_FEATS 40
#define DIM 8
#define GT_TILES ((N_NODES + 63) / 64)            // 782 gemm tiles
#define FILL_BLOCKS (N_EDGES / 256)               // 3125 fill blocks, 1 edge/thread
#define SCHUNK 52                                  // per-thread scan chunk (4-aligned)
#define CUR_STRIDE 4                               // cursor padded to 16B/counter

typedef _Float16 half8 __attribute__((ext_vector_type(8)));
typedef float floatx4 __attribute__((ext_vector_type(4)));

// ---------------- wave-wide inclusive scan (64 lanes) ----------------
__device__ __forceinline__ int wave_incl_scan(int x, int lane) {
#pragma unroll
    for (int off = 1; off < 64; off <<= 1) {
        int v = __shfl_up(x, off, 64);
        if (lane >= off) x += v;
    }
    return x;
}

// ============================================================================
// K1: in-degree histogram only. int4 loads, 4 edges/thread.
// Atomics are non-returning (fire-and-forget): no wait in the wave.
// ============================================================================
__global__ __launch_bounds__(256) void hist_kernel(const int* __restrict__ dst,
                                                   int* __restrict__ counts) {
    int i = blockIdx.x * 256 + threadIdx.x;      // quad index
    if (i * 4 >= N_EDGES) return;
    int4 d = ((const int4*)dst)[i];
    atomicAdd(&counts[d.x], 1);
    atomicAdd(&counts[d.y], 1);
    atomicAdd(&counts[d.z], 1);
    atomicAdd(&counts[d.w], 1);
}

// ============================================================================
// K2: single-block STREAMING two-pass scan. 1024 threads, no register hold
// (the register-resident version forced ~80 VGPR/thread of scratch spill at
// 16 waves/block). Pass A: per-thread sums. Pass B: re-read + write prefixes.
// Writes dense offsets[] (for aggs) and line-padded cursor[] (for fill).
// ============================================================================
__global__ __launch_bounds__(1024) void scan_kernel(const int* __restrict__ counts,
                                                    int* __restrict__ offsets,
                                                    int* __restrict__ cursor) {
    const int tid = threadIdx.x;
    const int lane = tid & 63, wid = tid >> 6;     // 16 waves
    const int beg = tid * SCHUNK;

    // pass A: sum this thread's chunk
    int s = 0;
#pragma unroll
    for (int j = 0; j < SCHUNK / 4; ++j) {
        int idx = beg + j * 4;
        if (idx < N_NODES) {                       // N_NODES % 4 == 0, full quad valid
            int4 c = *(const int4*)(counts + idx);
            s += c.x + c.y + c.z + c.w;
        }
    }

    // block-wide exclusive base
    __shared__ int wsum[16];
    int incl = wave_incl_scan(s, lane);
    if (lane == 63) wsum[wid] = incl;
    __syncthreads();
    if (wid == 0) {
        int v = (lane < 16) ? wsum[lane] : 0;
        int sc = wave_incl_scan(v, lane);
        if (lane < 16) wsum[lane] = sc;
    }
    __syncthreads();
    int run = ((wid > 0) ? wsum[wid - 1] : 0) + incl - s;

    // pass B: re-read (L2-warm) and emit prefixes
#pragma unroll
    for (int j = 0; j < SCHUNK / 4; ++j) {
        int idx = beg + j * 4;
        if (idx < N_NODES) {
            int4 v = *(const int4*)(counts + idx);
            int4 o;
            o.x = run; run += v.x;
            o.y = run; run += v.y;
            o.z = run; run += v.z;
            o.w = run; run += v.w;
            *(int4*)(offsets + idx) = o;
            cursor[(idx + 0) * CUR_STRIDE] = o.x;
            cursor[(idx + 1) * CUR_STRIDE] = o.y;
            cursor[(idx + 2) * CUR_STRIDE] = o.z;
            cursor[(idx + 3) * CUR_STRIDE] = o.w;
        }
    }
    if (tid == 0) offsets[N_NODES] = N_EDGES;
}

// ============================================================================
// K3: gemm1 MFMA tiles FIRST (R0's best ordering), then CSR fill blocks.
// Fill: 1 edge/thread, padded cursor (4 counters per 64B line instead of 16).
// ============================================================================
__global__ __launch_bounds__(256) void fillgemm_kernel(
    const float* __restrict__ features, const float* __restrict__ W1,
    const int* __restrict__ src, const int* __restrict__ dst,
    const float* __restrict__ ew,
    const float* __restrict__ mu1, const float* __restrict__ is1,
    const float* __restrict__ mu2, const float* __restrict__ is2,
    int* __restrict__ cursor, int2* __restrict__ csr,
    __half* __restrict__ h1)
{
    const int tid = threadIdx.x;
    __shared__ __align__(16) __half WT[64][136];   // W1^T fp16, 17.4 KB

    if (blockIdx.x >= GT_TILES) {
        // ---- fill: one edge per thread (3125*256 == 800000 exactly) ----
        int e = (blockIdx.x - GT_TILES) * 256 + tid;
        int sN = src[e];
        int dN = dst[e];
        const float4* ew4 = (const float4*)(ew + (size_t)e * DIM);
        float4 wa = ew4[0], wb = ew4[1];
        float v[8] = {wa.x, wa.y, wa.z, wa.w, wb.x, wb.y, wb.z, wb.w};
        float s1 = 0.f, s2 = 0.f;
#pragma unroll
        for (int d = 0; d < DIM; ++d) {
            float d1 = v[d] - mu1[d]; float a1 = is1[d];
            float d2 = v[d] - mu2[d]; float a2 = is2[d];
            s1 += d1 * d1 * a1 * a1;
            s2 += d2 * d2 * a2 * a2;
        }
        __half2 g = __floats2half2_rn(expf(-0.5f * s1), expf(-0.5f * s2));
        int2 rec;
        rec.x = sN;
        rec.y = *reinterpret_cast<int*>(&g);
        int pos = atomicAdd(&cursor[dN * CUR_STRIDE], 1);
        csr[pos] = rec;
        return;
    }

    // ---- gemm1 tile: 64 nodes x 64 feats, MFMA 16x16x32 f16, A from global ----
    int nodeBase = blockIdx.x * 64;
    for (int rep = 0; rep < 32; ++rep) {
        int idx = tid + rep * 256;          // 0..8191 = k*64 + n
        int k = idx >> 6, n = idx & 63;
        WT[n][k] = __float2half(W1[idx]);
    }
    __syncthreads();

    int lane = tid & 63, w = tid >> 6;
    int m = lane & 15, quad = lane >> 4;
    int row = nodeBase + w * 16 + m;
    int rowc = (row < N_NODES) ? row : (N_NODES - 1);
    const float* fr = features + (size_t)rowc * IN_FEATS;

    floatx4 acc0 = {0.f,0.f,0.f,0.f}, acc1 = acc0, acc2 = acc0, acc3 = acc0;
#pragma unroll
    for (int kc = 0; kc < 4; ++kc) {
        float4 fa = *(const float4*)(fr + kc * 32 + quad * 8);
        float4 fb = *(const float4*)(fr + kc * 32 + quad * 8 + 4);
        union { half8 v; __half2 h2[4]; } A;
        A.h2[0] = __floats2half2_rn(fa.x, fa.y);
        A.h2[1] = __floats2half2_rn(fa.z, fa.w);
        A.h2[2] = __floats2half2_rn(fb.x, fb.y);
        A.h2[3] = __floats2half2_rn(fb.z, fb.w);
        half8 b0 = *(const half8*)&WT[ 0 + m][kc * 32 + quad * 8];
        half8 b1 = *(const half8*)&WT[16 + m][kc * 32 + quad * 8];
        half8 b2 = *(const half8*)&WT[32 + m][kc * 32 + quad * 8];
        half8 b3 = *(const half8*)&WT[48 + m][kc * 32 + quad * 8];
        acc0 = __builtin_amdgcn_mfma_f32_16x16x32_f16(A.v, b0, acc0, 0, 0, 0);
        acc1 = __builtin_amdgcn_mfma_f32_16x16x32_f16(A.v, b1, acc1, 0, 0, 0);
        acc2 = __builtin_amdgcn_mfma_f32_16x16x32_f16(A.v, b2, acc2, 0, 0, 0);
        acc3 = __builtin_amdgcn_mfma_f32_16x16x32_f16(A.v, b3, acc3, 0, 0, 0);
    }
    int nodeRow = nodeBase + w * 16 + quad * 4;
#pragma unroll
    for (int r = 0; r < 4; ++r) {
        int n = nodeRow + r;
        if (n < N_NODES) {
            size_t base = (size_t)n * N_HIDDEN + m;
            h1[base +  0] = __float2half(acc0[r]);
            h1[base + 16] = __float2half(acc1[r]);
            h1[base + 32] = __float2half(acc2[r]);
            h1[base + 48] = __float2half(acc3[r]);
        }
    }
}

// ---------------- agg1 + gemm2 fused: 2 nodes per wave, packed fp16 pairs ----------
__global__ __launch_bounds__(256) void agg1_gemm2_kernel(const __half* __restrict__ h,
                                                         const int* __restrict__ offsets,
                                                         const int2* __restrict__ csr,
                                                         const float* __restrict__ b,
                                                         const float* __restrict__ W2,
                                                         __half* __restrict__ h2) {
    __shared__ float xs[8][64];
    const unsigned* h32 = (const unsigned*)h;   // h1 row = 32 dwords
    const int tid = threadIdx.x;
    const int w = tid >> 6, lane = tid & 63;
    const int hf = lane >> 5, p = lane & 31;
    const int ln = w * 2 + hf;                  // local node 0..7
    const int n = blockIdx.x * 8 + ln;
    int beg = offsets[n], end = offsets[n + 1];

    float ax = 0.f, ay = 0.f;
    int j = beg;
    for (; j + 4 <= end; j += 4) {
        int2 r0 = csr[j + 0], r1 = csr[j + 1], r2 = csr[j + 2], r3 = csr[j + 3];
        unsigned v0 = h32[(size_t)r0.x * 32 + p];
        unsigned v1 = h32[(size_t)r1.x * 32 + p];
        unsigned v2 = h32[(size_t)r2.x * 32 + p];
        unsigned v3 = h32[(size_t)r3.x * 32 + p];
        float g0 = __low2float(*reinterpret_cast<__half2*>(&r0.y));
        float g1 = __low2float(*reinterpret_cast<__half2*>(&r1.y));
        float g2 = __low2float(*reinterpret_cast<__half2*>(&r2.y));
        float g3 = __low2float(*reinterpret_cast<__half2*>(&r3.y));
        float2 f0 = __half22float2(*reinterpret_cast<__half2*>(&v0));
        float2 f1 = __half22float2(*reinterpret_cast<__half2*>(&v1));
        float2 f2 = __half22float2(*reinterpret_cast<__half2*>(&v2));
        float2 f3 = __half22float2(*reinterpret_cast<__half2*>(&v3));
        ax += f0.x * g0; ay += f0.y * g0;
        ax += f1.x * g1; ay += f1.y * g1;
        ax += f2.x * g2; ay += f2.y * g2;
        ax += f3.x * g3; ay += f3.y * g3;
    }
    for (; j < end; ++j) {
        int2 r = csr[j];
        unsigned v = h32[(size_t)r.x * 32 + p];
        float g = __low2float(*reinterpret_cast<__half2*>(&r.y));
        float2 f = __half22float2(*reinterpret_cast<__half2*>(&v));
        ax += f.x * g; ay += f.y * g;
    }
    float2 bb = *(const float2*)&b[2 * p];
    *(float2*)&xs[ln][2 * p] = make_float2(ax + bb.x, ay + bb.y);
    __syncthreads();

    // gemm2: 8 nodes x 40 outs = 320 outputs over 256 threads
    for (int o = tid; o < 8 * OUT_FEATS; o += 256) {
        int node = o / OUT_FEATS, t = o % OUT_FEATS;
        const float* xr = xs[node];
        float acc = 0.f;
#pragma unroll
        for (int k = 0; k < N_HIDDEN; ++k)
            acc += xr[k] * W2[k * OUT_FEATS + t];
        h2[(size_t)(blockIdx.x * 8 + node) * OUT_FEATS + t] = __float2half(acc);
    }
}

// ---------------- agg layer 2 + b2 + log_softmax: 2 nodes per wave ----------------
__global__ __launch_bounds__(256) void agg2_kernel(const __half* __restrict__ h,
                                                   const int* __restrict__ offsets,
                                                   const int2* __restrict__ csr,
                                                   const float* __restrict__ b,
                                                   float* __restrict__ out) {
    const unsigned* h32 = (const unsigned*)h;   // h2 row = 20 dwords
    const int tid = threadIdx.x;
    const int w = tid >> 6, lane = tid & 63;
    const int hf = lane >> 5, p = lane & 31;
    const int n = blockIdx.x * 8 + w * 2 + hf;
    const int pc = (p < 20) ? p : 19;           // clamp: no divergence, no OOB
    int beg = offsets[n], end = offsets[n + 1];

    float ax = 0.f, ay = 0.f;
    int j = beg;
    for (; j + 4 <= end; j += 4) {
        int2 r0 = csr[j + 0], r1 = csr[j + 1], r2 = csr[j + 2], r3 = csr[j + 3];
        unsigned v0 = h32[(size_t)r0.x * 20 + pc];
        unsigned v1 = h32[(size_t)r1.x * 20 + pc];
        unsigned v2 = h32[(size_t)r2.x * 20 + pc];
        unsigned v3 = h32[(size_t)r3.x * 20 + pc];
        float g0 = __high2float(*reinterpret_cast<__half2*>(&r0.y));
        float g1 = __high2float(*reinterpret_cast<__half2*>(&r1.y));
        float g2 = __high2float(*reinterpret_cast<__half2*>(&r2.y));
        float g3 = __high2float(*reinterpret_cast<__half2*>(&r3.y));
        float2 f0 = __half22float2(*reinterpret_cast<__half2*>(&v0));
        float2 f1 = __half22float2(*reinterpret_cast<__half2*>(&v1));
        float2 f2 = __half22float2(*reinterpret_cast<__half2*>(&v2));
        float2 f3 = __half22float2(*reinterpret_cast<__half2*>(&v3));
        ax += f0.x * g0; ay += f0.y * g0;
        ax += f1.x * g1; ay += f1.y * g1;
        ax += f2.x * g2; ay += f2.y * g2;
        ax += f3.x * g3; ay += f3.y * g3;
    }
    for (; j < end; ++j) {
        int2 r = csr[j];
        unsigned v = h32[(size_t)r.x * 20 + pc];
        float g = __high2float(*reinterpret_cast<__half2*>(&r.y));
        float2 f = __half22float2(*reinterpret_cast<__half2*>(&v));
        ax += f.x * g; ay += f.y * g;
    }

    bool valid = (p < 20);
    float vx = valid ? ax + b[2 * p]     : -INFINITY;
    float vy = valid ? ay + b[2 * p + 1] : -INFINITY;
    float m = fmaxf(vx, vy);
#pragma unroll
    for (int off = 16; off; off >>= 1)
        m = fmaxf(m, __shfl_xor(m, off, 32));   // reduce within each 32-lane half
    float ex = valid ? (expf(vx - m) + expf(vy - m)) : 0.f;
#pragma unroll
    for (int off = 16; off; off >>= 1)
        ex += __shfl_xor(ex, off, 32);
    float ls = logf(ex);
    if (valid) {
        float2 o = make_float2(vx - m - ls, vy - m - ls);
        *(float2*)&out[(size_t)n * OUT_FEATS + 2 * p] = o;
    }
}

extern "C" void kernel_launch(void* const* d_in, const int* in_sizes, int n_in,
                              void* d_out, int out_size, void* d_ws, size_t ws_size,
                              hipStream_t stream) {
    const float* features    = (const float*)d_in[0];
    const float* edge_weight = (const float*)d_in[1];
    const int*   src         = (const int*)d_in[2];
    const int*   dst         = (const int*)d_in[3];
    const float* W1          = (const float*)d_in[4];
    const float* b1          = (const float*)d_in[5];
    const float* mu1         = (const float*)d_in[6];
    const float* is1         = (const float*)d_in[7];
    const float* W2          = (const float*)d_in[8];
    const float* b2          = (const float*)d_in[9];
    const float* mu2         = (const float*)d_in[10];
    const float* is2         = (const float*)d_in[11];
    float* out = (float*)d_out;

    // Workspace: csr int2[800k] | h1 half[3.2M] | h2 half[2M]
    //            | counts[50k] | cursor[50k*4 padded] | offsets[50k+1]   (~18.0 MB)
    int2*   csr     = (int2*)d_ws;
    __half* h1      = (__half*)(csr + N_EDGES);
    __half* h2      = h1 + (size_t)N_NODES * N_HIDDEN;
    int*    counts  = (int*)(h2 + (size_t)N_NODES * OUT_FEATS);
    int*    cursor  = counts + N_NODES;
    int*    offsets = cursor + N_NODES * CUR_STRIDE;

    hipMemsetAsync(counts, 0, N_NODES * sizeof(int), stream);

    hist_kernel<<<(N_EDGES / 4 + 255) / 256, 256, 0, stream>>>(dst, counts);

    scan_kernel<<<1, 1024, 0, stream>>>(counts, offsets, cursor);

    fillgemm_kernel<<<GT_TILES + FILL_BLOCKS, 256, 0, stream>>>(
        features, W1, src, dst, edge_weight, mu1, is1, mu2, is2, cursor, csr, h1);

    agg1_gemm2_kernel<<<N_NODES / 8, 256, 0, stream>>>(h1, offsets, csr, b1, W2, h2);

    agg2_kernel<<<N_NODES / 8, 256, 0, stream>>>(h2, offsets, csr, b2, out);
}

// Round 4
// 236.395 us; speedup vs baseline: 1.2680x; 1.2680x over previous
//
#include <hip/hip_runtime.h>
#include <hip/hip_fp16.h>
#include <math.h>

#define N_NODES 50000
#define N_EDGES 800000
#define IN_FEATS 128
#define N_HIDDEN 64
#define OUT_FEATS 40
#define DIM 8
#define GT_TILES ((N_NODES + 63) / 64)            // 782 gemm tiles
#define FILL_BLOCKS (N_EDGES / 256)               // 3125 fill blocks, 1 edge/thread
#define SCAN_NB ((N_NODES + 255) / 256)           // 196 scan blocks

typedef _Float16 half8 __attribute__((ext_vector_type(8)));
typedef float floatx4 __attribute__((ext_vector_type(4)));

// ---------------- wave-wide inclusive scan (64 lanes) ----------------
__device__ __forceinline__ int wave_incl_scan(int x, int lane) {
#pragma unroll
    for (int off = 1; off < 64; off <<= 1) {
        int v = __shfl_up(x, off, 64);
        if (lane >= off) x += v;
    }
    return x;
}

// ============================================================================
// K1: in-degree histogram + per-edge rank. The atomic RETURNS the edge's rank
// within its dst node, so the fill kernel needs no atomic at all.
// ============================================================================
__global__ __launch_bounds__(256) void hist_kernel(const int* __restrict__ dst,
                                                   int* __restrict__ counts,
                                                   unsigned short* __restrict__ rank) {
    int i = blockIdx.x * 256 + threadIdx.x;      // quad index
    if (i * 4 >= N_EDGES) return;
    int4 d = ((const int4*)dst)[i];
    ushort4 r;
    r.x = (unsigned short)atomicAdd(&counts[d.x], 1);
    r.y = (unsigned short)atomicAdd(&counts[d.y], 1);
    r.z = (unsigned short)atomicAdd(&counts[d.z], 1);
    r.w = (unsigned short)atomicAdd(&counts[d.w], 1);
    ((ushort4*)rank)[i] = r;                      // coalesced 8B store
}

// ============================================================================
// K2a/b/c: hierarchical scan. Single-block scans are a ~50us floor (one CU
// sustains ~20 GB/s); this trio keeps every phase wide.
// ============================================================================
__global__ __launch_bounds__(256) void scan_partial_kernel(const int* __restrict__ counts,
                                                           int* __restrict__ offsets,
                                                           int* __restrict__ partials) {
    const int tid = threadIdx.x, bid = blockIdx.x;
    const int i = bid * 256 + tid;
    const int lane = tid & 63, wid = tid >> 6;
    int x = (i < N_NODES) ? counts[i] : 0;
    int incl = wave_incl_scan(x, lane);
    __shared__ int wsum[4];
    if (lane == 63) wsum[wid] = incl;
    __syncthreads();
    int base = 0;
#pragma unroll
    for (int w = 0; w < 4; ++w)
        if (w < wid) base += wsum[w];
    if (i < N_NODES) offsets[i] = base + incl - x;   // block-local exclusive
    if (tid == 255) partials[bid] = base + incl;     // block total
}

__global__ __launch_bounds__(256) void scan_base_kernel(int* __restrict__ partials) {
    const int tid = threadIdx.x;
    const int lane = tid & 63, wid = tid >> 6;
    int x = (tid < SCAN_NB) ? partials[tid] : 0;
    int incl = wave_incl_scan(x, lane);
    __shared__ int wsum[4];
    if (lane == 63) wsum[wid] = incl;
    __syncthreads();
    int base = 0;
#pragma unroll
    for (int w = 0; w < 4; ++w)
        if (w < wid) base += wsum[w];
    if (tid < SCAN_NB) partials[tid] = base + incl - x;  // exclusive base per block
}

__global__ __launch_bounds__(256) void scan_add_kernel(int* __restrict__ offsets,
                                                       const int* __restrict__ partials) {
    const int i = blockIdx.x * 256 + threadIdx.x;
    if (i < N_NODES) offsets[i] += partials[blockIdx.x];
    if (i == N_NODES) offsets[N_NODES] = N_EDGES;    // block 195 covers i==50000
}

// ============================================================================
// K3: gemm1 MFMA tiles first, then ATOMIC-FREE CSR fill.
// pos = offsets[dst] + rank[e]; csr record streamed out nontemporally
// (read exactly once by agg1 -> skip L2 allocate/RFO).
// ============================================================================
__global__ __launch_bounds__(256) void fillgemm_kernel(
    const float* __restrict__ features, const float* __restrict__ W1,
    const int* __restrict__ src, const int* __restrict__ dst,
    const float* __restrict__ ew,
    const float* __restrict__ mu1, const float* __restrict__ is1,
    const float* __restrict__ mu2, const float* __restrict__ is2,
    const int* __restrict__ offsets, const unsigned short* __restrict__ rank,
    int2* __restrict__ csr, __half* __restrict__ h1)
{
    const int tid = threadIdx.x;
    __shared__ __align__(16) __half WT[64][136];   // W1^T fp16, 17.4 KB

    if (blockIdx.x >= GT_TILES) {
        // ---- fill: one edge per thread (3125*256 == 800000 exactly) ----
        int e = (blockIdx.x - GT_TILES) * 256 + tid;
        int sN = src[e];
        int dN = dst[e];
        unsigned short rk = rank[e];
        const float4* ew4 = (const float4*)(ew + (size_t)e * DIM);
        float4 wa = ew4[0], wb = ew4[1];
        float v[8] = {wa.x, wa.y, wa.z, wa.w, wb.x, wb.y, wb.z, wb.w};
        float s1 = 0.f, s2 = 0.f;
#pragma unroll
        for (int d = 0; d < DIM; ++d) {
            float d1 = v[d] - mu1[d]; float a1 = is1[d];
            float d2 = v[d] - mu2[d]; float a2 = is2[d];
            s1 += d1 * d1 * a1 * a1;
            s2 += d2 * d2 * a2 * a2;
        }
        __half2 g = __floats2half2_rn(expf(-0.5f * s1), expf(-0.5f * s2));
        int2 rec;
        rec.x = sN;
        rec.y = *reinterpret_cast<int*>(&g);
        int pos = offsets[dN] + rk;                 // offsets: 200KB, L2-hot
        __builtin_nontemporal_store(*reinterpret_cast<long long*>(&rec),
                                    reinterpret_cast<long long*>(&csr[pos]));
        return;
    }

    // ---- gemm1 tile: 64 nodes x 64 feats, MFMA 16x16x32 f16, A from global ----
    int nodeBase = blockIdx.x * 64;
    for (int rep = 0; rep < 32; ++rep) {
        int idx = tid + rep * 256;          // 0..8191 = k*64 + n
        int k = idx >> 6, n = idx & 63;
        WT[n][k] = __float2half(W1[idx]);
    }
    __syncthreads();

    int lane = tid & 63, w = tid >> 6;
    int m = lane & 15, quad = lane >> 4;
    int row = nodeBase + w * 16 + m;
    int rowc = (row < N_NODES) ? row : (N_NODES - 1);
    const float* fr = features + (size_t)rowc * IN_FEATS;

    floatx4 acc0 = {0.f,0.f,0.f,0.f}, acc1 = acc0, acc2 = acc0, acc3 = acc0;
#pragma unroll
    for (int kc = 0; kc < 4; ++kc) {
        float4 fa = *(const float4*)(fr + kc * 32 + quad * 8);
        float4 fb = *(const float4*)(fr + kc * 32 + quad * 8 + 4);
        union { half8 v; __half2 h2[4]; } A;
        A.h2[0] = __floats2half2_rn(fa.x, fa.y);
        A.h2[1] = __floats2half2_rn(fa.z, fa.w);
        A.h2[2] = __floats2half2_rn(fb.x, fb.y);
        A.h2[3] = __floats2half2_rn(fb.z, fb.w);
        half8 b0 = *(const half8*)&WT[ 0 + m][kc * 32 + quad * 8];
        half8 b1 = *(const half8*)&WT[16 + m][kc * 32 + quad * 8];
        half8 b2 = *(const half8*)&WT[32 + m][kc * 32 + quad * 8];
        half8 b3 = *(const half8*)&WT[48 + m][kc * 32 + quad * 8];
        acc0 = __builtin_amdgcn_mfma_f32_16x16x32_f16(A.v, b0, acc0, 0, 0, 0);
        acc1 = __builtin_amdgcn_mfma_f32_16x16x32_f16(A.v, b1, acc1, 0, 0, 0);
        acc2 = __builtin_amdgcn_mfma_f32_16x16x32_f16(A.v, b2, acc2, 0, 0, 0);
        acc3 = __builtin_amdgcn_mfma_f32_16x16x32_f16(A.v, b3, acc3, 0, 0, 0);
    }
    int nodeRow = nodeBase + w * 16 + quad * 4;
#pragma unroll
    for (int r = 0; r < 4; ++r) {
        int n = nodeRow + r;
        if (n < N_NODES) {
            size_t base = (size_t)n * N_HIDDEN + m;
            h1[base +  0] = __float2half(acc0[r]);
            h1[base + 16] = __float2half(acc1[r]);
            h1[base + 32] = __float2half(acc2[r]);
            h1[base + 48] = __float2half(acc3[r]);
        }
    }
}

// ---------------- agg1 + gemm2 fused: 2 nodes per wave, packed fp16 pairs ----------
__global__ __launch_bounds__(256) void agg1_gemm2_kernel(const __half* __restrict__ h,
                                                         const int* __restrict__ offsets,
                                                         const int2* __restrict__ csr,
                                                         const float* __restrict__ b,
                                                         const float* __restrict__ W2,
                                                         __half* __restrict__ h2) {
    __shared__ float xs[8][64];
    const unsigned* h32 = (const unsigned*)h;   // h1 row = 32 dwords
    const int tid = threadIdx.x;
    const int w = tid >> 6, lane = tid & 63;
    const int hf = lane >> 5, p = lane & 31;
    const int ln = w * 2 + hf;                  // local node 0..7
    const int n = blockIdx.x * 8 + ln;
    int beg = offsets[n], end = offsets[n + 1];

    float ax = 0.f, ay = 0.f;
    int j = beg;
    for (; j + 4 <= end; j += 4) {
        int2 r0 = csr[j + 0], r1 = csr[j + 1], r2 = csr[j + 2], r3 = csr[j + 3];
        unsigned v0 = h32[(size_t)r0.x * 32 + p];
        unsigned v1 = h32[(size_t)r1.x * 32 + p];
        unsigned v2 = h32[(size_t)r2.x * 32 + p];
        unsigned v3 = h32[(size_t)r3.x * 32 + p];
        float g0 = __low2float(*reinterpret_cast<__half2*>(&r0.y));
        float g1 = __low2float(*reinterpret_cast<__half2*>(&r1.y));
        float g2 = __low2float(*reinterpret_cast<__half2*>(&r2.y));
        float g3 = __low2float(*reinterpret_cast<__half2*>(&r3.y));
        float2 f0 = __half22float2(*reinterpret_cast<__half2*>(&v0));
        float2 f1 = __half22float2(*reinterpret_cast<__half2*>(&v1));
        float2 f2 = __half22float2(*reinterpret_cast<__half2*>(&v2));
        float2 f3 = __half22float2(*reinterpret_cast<__half2*>(&v3));
        ax += f0.x * g0; ay += f0.y * g0;
        ax += f1.x * g1; ay += f1.y * g1;
        ax += f2.x * g2; ay += f2.y * g2;
        ax += f3.x * g3; ay += f3.y * g3;
    }
    for (; j < end; ++j) {
        int2 r = csr[j];
        unsigned v = h32[(size_t)r.x * 32 + p];
        float g = __low2float(*reinterpret_cast<__half2*>(&r.y));
        float2 f = __half22float2(*reinterpret_cast<__half2*>(&v));
        ax += f.x * g; ay += f.y * g;
    }
    float2 bb = *(const float2*)&b[2 * p];
    *(float2*)&xs[ln][2 * p] = make_float2(ax + bb.x, ay + bb.y);
    __syncthreads();

    // gemm2: 8 nodes x 40 outs = 320 outputs over 256 threads
    for (int o = tid; o < 8 * OUT_FEATS; o += 256) {
        int node = o / OUT_FEATS, t = o % OUT_FEATS;
        const float* xr = xs[node];
        float acc = 0.f;
#pragma unroll
        for (int k = 0; k < N_HIDDEN; ++k)
            acc += xr[k] * W2[k * OUT_FEATS + t];
        h2[(size_t)(blockIdx.x * 8 + node) * OUT_FEATS + t] = __float2half(acc);
    }
}

// ---------------- agg layer 2 + b2 + log_softmax: 2 nodes per wave ----------------
__global__ __launch_bounds__(256) void agg2_kernel(const __half* __restrict__ h,
                                                   const int* __restrict__ offsets,
                                                   const int2* __restrict__ csr,
                                                   const float* __restrict__ b,
                                                   float* __restrict__ out) {
    const unsigned* h32 = (const unsigned*)h;   // h2 row = 20 dwords
    const int tid = threadIdx.x;
    const int w = tid >> 6, lane = tid & 63;
    const int hf = lane >> 5, p = lane & 31;
    const int n = blockIdx.x * 8 + w * 2 + hf;
    const int pc = (p < 20) ? p : 19;           // clamp: no divergence, no OOB
    int beg = offsets[n], end = offsets[n + 1];

    float ax = 0.f, ay = 0.f;
    int j = beg;
    for (; j + 4 <= end; j += 4) {
        int2 r0 = csr[j + 0], r1 = csr[j + 1], r2 = csr[j + 2], r3 = csr[j + 3];
        unsigned v0 = h32[(size_t)r0.x * 20 + pc];
        unsigned v1 = h32[(size_t)r1.x * 20 + pc];
        unsigned v2 = h32[(size_t)r2.x * 20 + pc];
        unsigned v3 = h32[(size_t)r3.x * 20 + pc];
        float g0 = __high2float(*reinterpret_cast<__half2*>(&r0.y));
        float g1 = __high2float(*reinterpret_cast<__half2*>(&r1.y));
        float g2 = __high2float(*reinterpret_cast<__half2*>(&r2.y));
        float g3 = __high2float(*reinterpret_cast<__half2*>(&r3.y));
        float2 f0 = __half22float2(*reinterpret_cast<__half2*>(&v0));
        float2 f1 = __half22float2(*reinterpret_cast<__half2*>(&v1));
        float2 f2 = __half22float2(*reinterpret_cast<__half2*>(&v2));
        float2 f3 = __half22float2(*reinterpret_cast<__half2*>(&v3));
        ax += f0.x * g0; ay += f0.y * g0;
        ax += f1.x * g1; ay += f1.y * g1;
        ax += f2.x * g2; ay += f2.y * g2;
        ax += f3.x * g3; ay += f3.y * g3;
    }
    for (; j < end; ++j) {
        int2 r = csr[j];
        unsigned v = h32[(size_t)r.x * 20 + pc];
        float g = __high2float(*reinterpret_cast<__half2*>(&r.y));
        float2 f = __half22float2(*reinterpret_cast<__half2*>(&v));
        ax += f.x * g; ay += f.y * g;
    }

    bool valid = (p < 20);
    float vx = valid ? ax + b[2 * p]     : -INFINITY;
    float vy = valid ? ay + b[2 * p + 1] : -INFINITY;
    float m = fmaxf(vx, vy);
#pragma unroll
    for (int off = 16; off; off >>= 1)
        m = fmaxf(m, __shfl_xor(m, off, 32));   // reduce within each 32-lane half
    float ex = valid ? (expf(vx - m) + expf(vy - m)) : 0.f;
#pragma unroll
    for (int off = 16; off; off >>= 1)
        ex += __shfl_xor(ex, off, 32);
    float ls = logf(ex);
    if (valid) {
        float2 o = make_float2(vx - m - ls, vy - m - ls);
        *(float2*)&out[(size_t)n * OUT_FEATS + 2 * p] = o;
    }
}

extern "C" void kernel_launch(void* const* d_in, const int* in_sizes, int n_in,
                              void* d_out, int out_size, void* d_ws, size_t ws_size,
                              hipStream_t stream) {
    const float* features    = (const float*)d_in[0];
    const float* edge_weight = (const float*)d_in[1];
    const int*   src         = (const int*)d_in[2];
    const int*   dst         = (const int*)d_in[3];
    const float* W1          = (const float*)d_in[4];
    const float* b1          = (const float*)d_in[5];
    const float* mu1         = (const float*)d_in[6];
    const float* is1         = (const float*)d_in[7];
    const float* W2          = (const float*)d_in[8];
    const float* b2          = (const float*)d_in[9];
    const float* mu2         = (const float*)d_in[10];
    const float* is2         = (const float*)d_in[11];
    float* out = (float*)d_out;

    // Workspace: csr int2[800k] 6.4M | h1 half[3.2M] 6.4M | h2 half[2M] 4M
    //            | counts[50k] 200K | rank u16[800k] 1.6M | offsets[50k+1] 200K
    //            | partials[256] 1K                                  (~18.8 MB)
    int2*           csr     = (int2*)d_ws;
    __half*         h1      = (__half*)(csr + N_EDGES);
    __half*         h2      = h1 + (size_t)N_NODES * N_HIDDEN;
    int*            counts  = (int*)(h2 + (size_t)N_NODES * OUT_FEATS);
    unsigned short* rank    = (unsigned short*)(counts + N_NODES);
    int*            offsets = (int*)(rank + N_EDGES);
    int*            partials= offsets + N_NODES + 1;

    hipMemsetAsync(counts, 0, N_NODES * sizeof(int), stream);

    hist_kernel<<<(N_EDGES / 4 + 255) / 256, 256, 0, stream>>>(dst, counts, rank);

    scan_partial_kernel<<<SCAN_NB, 256, 0, stream>>>(counts, offsets, partials);
    scan_base_kernel<<<1, 256, 0, stream>>>(partials);
    scan_add_kernel<<<SCAN_NB, 256, 0, stream>>>(offsets, partials);

    fillgemm_kernel<<<GT_TILES + FILL_BLOCKS, 256, 0, stream>>>(
        features, W1, src, dst, edge_weight, mu1, is1, mu2, is2, offsets, rank, csr, h1);

    agg1_gemm2_kernel<<<N_NODES / 8, 256, 0, stream>>>(h1, offsets, csr, b1, W2, h2);

    agg2_kernel<<<N_NODES / 8, 256, 0, stream>>>(h2, offsets, csr, b2, out);
}